// Round 2
// baseline (134.764 us; speedup 1.0000x reference)
//
#include <hip/hip_runtime.h>
#include <hip/hip_cooperative_groups.h>

namespace cg = cooperative_groups;

#define Bn 32
#define Cn 64
#define Hn 56
#define Wn 56
#define REPN 50
#define NKn 17
#define HWn (Hn*Wn)           // 3136
#define NSTATf 100352.0f      // B*H*W
#define EPSf 1e-5f

// ws layout (floats) — every slot written unconditionally before any read
#define PART_OFF 0            // [q(6)][r(50)][b(32)] = 9600
#define WEFF_OFF 9600         // [r(50)][ij(9)][t(8)] = 3600 (t=7 is zero pad)
#define WEFF_N   (REPN*72)

#define SEGH 7
#define NTASK 112             // 8 row-segments * 14 quad-cols
#define GRID_FUSED 2048       // == B*C, one task per block per phase

// ------------------------------------------------------------ weff compute
// Transposed layout: ws[WEFF_OFF + r*72 + ij*8 + t], t in [0,7), pad t==7 -> 0.
// t meaning: 0..2 = Mh shifts, 3..5 = Mv shifts, 6 = Mid.
__device__ __forceinline__ void weff_one(int idx,
        const float* __restrict__ w0, const float* __restrict__ w1,
        const int* __restrict__ Mh, const int* __restrict__ Mv,
        const int* __restrict__ Mid, float* __restrict__ ws)
{
    int r   = idx / 72;
    int rem = idx % 72;
    int ij  = rem >> 3;
    int t   = rem & 7;
    if (t == 7) { ws[WEFF_OFF + idx] = 0.f; return; }
    const int* M = (t < 3) ? (Mh + (t*REPN + r)*NKn)
                 : (t < 6) ? (Mv + ((t-3)*REPN + r)*NKn)
                           : (Mid + r*NKn);
    float acc = 0.f;
    #pragma unroll
    for (int k = 0; k < NKn; ++k)
        acc += (float)M[k] * (w0[(r*NKn + k)*9 + ij] + w1[(r*NKn + k)*9 + ij]);
    ws[WEFF_OFF + idx] = acc;
}

__global__ void k_weff(const float* __restrict__ w0, const float* __restrict__ w1,
                       const int* __restrict__ Mh, const int* __restrict__ Mv,
                       const int* __restrict__ Mid, float* __restrict__ ws)
{
    int idx = blockIdx.x * blockDim.x + threadIdx.x;
    if (idx < WEFF_N) weff_one(idx, w0, w1, Mh, Mv, Mid, ws);
}

// Load input row `row` of channel ch as window X[0..7] = cols 4q-3..4q+4
// (zeros outside [0,56)). Also c55 = input[row][55] for q==0 lanes.
__device__ __forceinline__ void load_row8c(const float* __restrict__ ch, int row, int q,
                                           float* __restrict__ X, float& c55)
{
    bool rv = (row >= 0) && (row < Hn);
    int rc = rv ? row : 0;
    const float* rp = ch + rc*Wn;
    float4 c0 = *(const float4*)(rp + (q ? 4*q - 4 : 0));   // cols 4q-4..4q-1
    float4 c1 = *(const float4*)(rp + 4*q);                 // cols 4q..4q+3
    int ox = (4*q + 4 <= 55) ? 4*q + 4 : 55;                // clamp in-row
    float cx = rp[ox];
    float mr = rv ? 1.f : 0.f;
    float m0 = (rv && q > 0)  ? 1.f : 0.f;
    float mx = (rv && q < 13) ? 1.f : 0.f;
    X[0]=c0.y*m0; X[1]=c0.z*m0; X[2]=c0.w*m0;
    X[3]=c1.x*mr; X[4]=c1.y*mr; X[5]=c1.z*mr; X[6]=c1.w*mr;
    X[7]=cx*mx;
    c55 = (q == 0) ? rp[55]*mr : 0.f;
}

// ---------------------------------------------------- register-walk conv core
// Weights come from LDS (swk, [ij][t] layout, 8-padded). Per row iteration an
// opaque zero (asm) prevents LICM from hoisting the 63 weight loads into
// long-lived registers (that hoist caused scratch spills at the 128-VGPR cap).
// Each 3x3 tap reads its 7 weights as two ds_read_b128 (wave-uniform address
// = LDS broadcast, conflict-free).
template <typename F>
__device__ __forceinline__ void conv_walk(const float* __restrict__ ch,
        const float* __restrict__ swk, int tid, F emit)
{
    if (tid >= NTASK) return;
    int seg = tid / 14;
    int q   = tid - seg*14;
    int h0  = seg * SEGH;
    bool top = (seg == 0);

    float W[5][8], C[5], T[8];
    {
        float dummy;
        if (top) load_row8c(ch, 55, q, T, dummy);
    }
    #pragma unroll
    for (int k = 0; k < 5; ++k)
        load_row8c(ch, h0 - 3 + k, q, W[k], C[k]);

    #pragma unroll
    for (int s = 0; s < SEGH; ++s) {
        int h = h0 + s;
        float Wn8[8], Cn1;
        load_row8c(ch, h + 2, q, Wn8, Cn1);   // prefetch next row

        int z = 0;
        asm volatile("" : "+v"(z));           // defeat LICM: reload weights per row
        const float* wz = swk + z;

        float l1[4], l2[4], sm[4];
        #pragma unroll
        for (int p = 0; p < 4; ++p) { l1[p]=0.f; l2[p]=0.f; sm[p]=0.f; }
        #pragma unroll
        for (int i = 0; i < 3; ++i)
            #pragma unroll
            for (int j = 0; j < 3; ++j) {
                int ij = i*3 + j;
                float4 wa = *(const float4*)(wz + ij*8);      // t0..t3
                float4 wb = *(const float4*)(wz + ij*8 + 4);  // t4..t6,pad
                float wh0 = wa.x, wh1 = wa.y, wh2 = wa.z, wv0 = wa.w;
                float wv1 = wb.x, wv2 = wb.y, wid = wb.z;
                #pragma unroll
                for (int p = 0; p < 4; ++p) {
                    float a  = W[2+i][p+2+j];     // pos0
                    l1[p] = fmaf(a, wh0, l1[p]);
                    l2[p] = fmaf(a, wv0, l2[p]);
                    sm[p] = fmaf(a, wid, sm[p]);
                    float bA = W[1+i][p+j];       // posA
                    l1[p] = fmaf(bA, wh1, l1[p]);
                    l2[p] = fmaf(bA, wv2, l2[p]);
                    float bB = W[i][p+1+j];       // posB
                    l1[p] = fmaf(bB, wh2, l1[p]);
                    l2[p] = fmaf(bB, wv1, l2[p]);
                }
            }
        if (q == 0) {   // col wrap, pixel 0 only: t=1 (wh1), t=5 (wv2) at j=0
            #pragma unroll
            for (int i = 0; i < 3; ++i) {
                l1[0] = fmaf(C[1+i], wz[(3*i)*8 + 1], l1[0]);
                l2[0] = fmaf(C[1+i], wz[(3*i)*8 + 5], l2[0]);
            }
        }
        if (s == 0 && top) {   // row wrap, h==0 only: t=2 (wh2), t=4 (wv1) at i=0
            #pragma unroll
            for (int j = 0; j < 3; ++j)
                #pragma unroll
                for (int p = 0; p < 4; ++p) {
                    l1[p] = fmaf(T[p+1+j], wz[j*8 + 2], l1[p]);
                    l2[p] = fmaf(T[p+1+j], wz[j*8 + 4], l2[p]);
                }
        }
        float res[4] = {W[3][3], W[3][4], W[3][5], W[3][6]};
        emit(h, q, l1, l2, sm, res);

        #pragma unroll
        for (int k = 0; k < 4; ++k) {
            #pragma unroll
            for (int x = 0; x < 8; ++x) W[k][x] = W[k+1][x];
            C[k] = C[k+1];
        }
        #pragma unroll
        for (int x = 0; x < 8; ++x) W[4][x] = Wn8[x];
        C[4] = Cn1;
    }
}

// ------------------------------------------- fused cooperative single kernel
// Grid 2048 x 128 (== B*C blocks, one (b,c) task per block per phase).
// __launch_bounds__(128,2): empirically hipcc maps 2nd arg N -> waves/EU=2N,
// i.e. VGPR cap = 256/N. N=2 -> cap 128 (no spill with weights in LDS);
// N=4 capped at 64 and spilled catastrophically (R1: 384 MB scratch traffic).
// With VGPR<=128 the HW fits 4 waves/EU = 16 waves/CU = 8 blocks/CU, exactly
// the co-residency the 2048-block cooperative launch needs.
// Phase 0: weff (29 blocks) + ghost copies (448 blocks) overlap. sync.
// Phase 1: stats partial, one (r,b) per block. sync.
// Phase 2: finalize BN, recompute conv, write output.
__global__ void __launch_bounds__(128, 2) k_fused(const float* __restrict__ in,
        const float* __restrict__ w0, const float* __restrict__ w1,
        const int* __restrict__ Mh, const int* __restrict__ Mv,
        const int* __restrict__ Mid,
        const int* __restrict__ rep_idx, const int* __restrict__ ghost_idx,
        float* __restrict__ ws, float* __restrict__ out)
{
    cg::grid_group grid = cg::this_grid();
    int tid = threadIdx.x;
    int v = blockIdx.x;           // 0..2047
    int c = v & 63;
    int b = v >> 6;
    bool ghost = (c >= REPN);

    __shared__ float swk[72];
    __shared__ float red[2][6];
    __shared__ float sred[6];

    // ---- phase 0: effective weights + ghost copies (independent, overlap)
    {
        int gidx = blockIdx.x * 128 + tid;
        if (gidx < WEFF_N) weff_one(gidx, w0, w1, Mh, Mv, Mid, ws);
    }
    if (ghost) {
        int cin = ghost_idx[c - REPN];
        const float4* s4 = (const float4*)(in + ((size_t)(b*Cn + cin))*HWn);
        float4* d4 = (float4*)(out + ((size_t)(b*Cn + c))*HWn);
        for (int i = tid; i < HWn/4; i += 128) d4[i] = s4[i];
    }
    grid.sync();

    // ---- phase 1: partial stats for (r=c, b)
    if (!ghost) {
        int r = c;
        if (tid < 72) swk[tid] = ws[WEFF_OFF + r*72 + tid];
        __syncthreads();
        const float* ch = in + ((size_t)(b*Cn + rep_idx[r]))*HWn;

        float s1=0.f,q1=0.f,s2=0.f,q2=0.f,s3=0.f,q3=0.f;
        conv_walk(ch, swk, tid,
            [&](int h, int q, float* l1, float* l2, float* sm, float* res) {
                (void)h; (void)q; (void)res;
                #pragma unroll
                for (int p = 0; p < 4; ++p) {
                    s1 += l1[p]; q1 += l1[p]*l1[p];
                    s2 += l2[p]; q2 += l2[p]*l2[p];
                    s3 += sm[p]; q3 += sm[p]*sm[p];
                }
            });
        {
            float vals[6] = {s1,q1,s2,q2,s3,q3};
            int lane = tid & 63, wave = tid >> 6;
            #pragma unroll
            for (int x = 0; x < 6; ++x) {
                float y = vals[x];
                for (int o = 32; o; o >>= 1) y += __shfl_down(y, o, 64);
                if (lane == 0) red[wave][x] = y;
            }
        }
        __syncthreads();
        if (tid < 6)
            ws[PART_OFF + (tid*REPN + c)*Bn + b] = red[0][tid] + red[1][tid];
    }
    grid.sync();

    // ---- phase 2: finalize BN + recompute conv + write
    if (ghost) return;
    int r = c;
    if (tid < 6) {
        const float* pp = ws + PART_OFF + (tid*REPN + r)*Bn;
        float s = 0.f;
        #pragma unroll
        for (int i = 0; i < Bn; ++i) s += pp[i];
        sred[tid] = s;
    }
    __syncthreads();
    const float inv = 1.0f / NSTATf;
    float m1 = sred[0]*inv, v1 = sred[1]*inv - m1*m1;
    float m2 = sred[2]*inv, v2 = sred[3]*inv - m2*m2;
    float m3 = sred[4]*inv, v3 = sred[5]*inv - m3*m3;
    float r1 = rsqrtf(v1 + EPSf), r2 = rsqrtf(v2 + EPSf), r3 = rsqrtf(v3 + EPSf);

    const float* ch = in + ((size_t)(b*Cn + rep_idx[r]))*HWn;
    float* dst = out + ((size_t)(b*Cn + c))*HWn;

    conv_walk(ch, swk, tid,
        [&](int h, int q, float* l1, float* l2, float* sm, float* res) {
            float4 o;
            o.x = (l1[0]-m1)*r1 + (l2[0]-m2)*r2 + (sm[0]-m3)*r3 + res[0];
            o.y = (l1[1]-m1)*r1 + (l2[1]-m2)*r2 + (sm[1]-m3)*r3 + res[1];
            o.z = (l1[2]-m1)*r1 + (l2[2]-m2)*r2 + (sm[2]-m3)*r3 + res[2];
            o.w = (l1[3]-m1)*r1 + (l2[3]-m2)*r2 + (sm[3]-m3)*r3 + res[3];
            *(float4*)(dst + h*Wn + 4*q) = o;
        });
}

// ------------------------------------- fallback kernels (3-kernel chain)
__global__ void __launch_bounds__(128) k_stats(const float* __restrict__ in,
        const int* __restrict__ rep_idx, float* __restrict__ ws)
{
    int bid = blockIdx.x;
    int r = bid % REPN;
    int b = bid / REPN;
    int tid = threadIdx.x;

    __shared__ float swk[72];
    if (tid < 72) swk[tid] = ws[WEFF_OFF + r*72 + tid];
    __syncthreads();
    const float* ch = in + ((size_t)(b*Cn + rep_idx[r]))*HWn;

    float s1=0.f,q1=0.f,s2=0.f,q2=0.f,s3=0.f,q3=0.f;
    conv_walk(ch, swk, tid,
        [&](int h, int q, float* l1, float* l2, float* sm, float* res) {
            (void)h; (void)q; (void)res;
            #pragma unroll
            for (int p = 0; p < 4; ++p) {
                s1 += l1[p]; q1 += l1[p]*l1[p];
                s2 += l2[p]; q2 += l2[p]*l2[p];
                s3 += sm[p]; q3 += sm[p]*sm[p];
            }
        });

    __shared__ float red[2][6];
    float vals[6] = {s1,q1,s2,q2,s3,q3};
    int lane = tid & 63, wave = tid >> 6;
    #pragma unroll
    for (int v = 0; v < 6; ++v) {
        float x = vals[v];
        for (int o = 32; o; o >>= 1) x += __shfl_down(x, o, 64);
        if (lane == 0) red[wave][v] = x;
    }
    __syncthreads();
    if (tid < 6)
        ws[PART_OFF + (tid*REPN + r)*Bn + b] = red[0][tid] + red[1][tid];
}

__global__ void __launch_bounds__(128) k_out(const float* __restrict__ in,
        const int* __restrict__ rep_idx, const int* __restrict__ ghost_idx,
        const float* __restrict__ ws, float* __restrict__ out)
{
    int bid = blockIdx.x;
    int c = bid % Cn;
    int b = bid / Cn;
    int tid = threadIdx.x;

    if (c >= REPN) {
        int cin = ghost_idx[c - REPN];
        const float4* s4 = (const float4*)(in + ((size_t)(b*Cn + cin))*HWn);
        float4* d4 = (float4*)(out + ((size_t)(b*Cn + c))*HWn);
        for (int i = tid; i < HWn/4; i += 128) d4[i] = s4[i];
        return;
    }

    int r = c;
    __shared__ float swk[72];
    __shared__ float sred[6];
    if (tid < 72) swk[tid] = ws[WEFF_OFF + r*72 + tid];
    if (tid < 6) {
        const float* pp = ws + PART_OFF + (tid*REPN + r)*Bn;
        float s = 0.f;
        #pragma unroll
        for (int i = 0; i < Bn; ++i) s += pp[i];
        sred[tid] = s;
    }
    __syncthreads();
    const float inv = 1.0f / NSTATf;
    float m1 = sred[0]*inv, v1 = sred[1]*inv - m1*m1;
    float m2 = sred[2]*inv, v2 = sred[3]*inv - m2*m2;
    float m3 = sred[4]*inv, v3 = sred[5]*inv - m3*m3;
    float r1 = rsqrtf(v1 + EPSf), r2 = rsqrtf(v2 + EPSf), r3 = rsqrtf(v3 + EPSf);

    const float* ch = in + ((size_t)(b*Cn + rep_idx[r]))*HWn;
    float* dst = out + ((size_t)(b*Cn + c))*HWn;

    conv_walk(ch, swk, tid,
        [&](int h, int q, float* l1, float* l2, float* sm, float* res) {
            float4 o;
            o.x = (l1[0]-m1)*r1 + (l2[0]-m2)*r2 + (sm[0]-m3)*r3 + res[0];
            o.y = (l1[1]-m1)*r1 + (l2[1]-m2)*r2 + (sm[1]-m3)*r3 + res[1];
            o.z = (l1[2]-m1)*r1 + (l2[2]-m2)*r2 + (sm[2]-m3)*r3 + res[2];
            o.w = (l1[3]-m1)*r1 + (l2[3]-m2)*r2 + (sm[3]-m3)*r3 + res[3];
            *(float4*)(dst + h*Wn + 4*q) = o;
        });
}

extern "C" void kernel_launch(void* const* d_in, const int* in_sizes, int n_in,
                              void* d_out, int out_size, void* d_ws, size_t ws_size,
                              hipStream_t stream) {
    const float* in   = (const float*)d_in[0];
    const float* w0   = (const float*)d_in[1];
    const float* w1   = (const float*)d_in[2];
    const int*   Mh   = (const int*)d_in[3];
    const int*   Mv   = (const int*)d_in[4];
    const int*   Mid  = (const int*)d_in[5];
    const int*   ghost= (const int*)d_in[6];
    const int*   rep  = (const int*)d_in[7];
    float* out  = (float*)d_out;
    float* ws   = (float*)d_ws;

    // Capture-safe occupancy gate: cooperative path needs 8 blocks/CU
    // (2048 blocks co-resident on 256 CUs).
    int maxBlk = 0;
    hipError_t qerr = hipOccupancyMaxActiveBlocksPerMultiprocessor(
        &maxBlk, (const void*)k_fused, 128, 0);
    bool coop_ok = (qerr == hipSuccess) && (maxBlk >= 8);

    if (coop_ok) {
        void* args[] = { (void*)&in, (void*)&w0, (void*)&w1, (void*)&Mh,
                         (void*)&Mv, (void*)&Mid, (void*)&rep, (void*)&ghost,
                         (void*)&ws, (void*)&out };
        hipError_t lerr = hipLaunchCooperativeKernel((const void*)k_fused,
                              dim3(GRID_FUSED), dim3(128), args, 0, stream);
        if (lerr == hipSuccess) return;
    }
    // Fallback: proven 3-kernel chain
    k_weff<<<(WEFF_N + 127)/128, 128, 0, stream>>>(w0, w1, Mh, Mv, Mid, ws);
    k_stats<<<Bn*REPN, 128, 0, stream>>>(in, rep, ws);
    k_out<<<Bn*Cn, 128, 0, stream>>>(in, rep, ghost, ws, out);
}

// Round 3
// 134.412 us; speedup vs baseline: 1.0026x; 1.0026x over previous
//
#include <hip/hip_runtime.h>

#define Bn 32
#define Cn 64
#define Hn 56
#define Wn 56
#define REPN 50
#define NKn 17
#define HWn (Hn*Wn)           // 3136
#define NSTATf 100352.0f      // B*H*W
#define EPSf 1e-5f

// ws layout (4-byte units). ws is POISONED by the harness between iterations,
// so k_init re-zeroes the atomic region at the head of every captured graph.
#define GSUM_OFF 0            // float [r(50)][8] = 400 (6 used per r)
#define GCNT_OFF 512          // unsigned [r(50)*32] = 1600 (128B stride per r)
#define INIT_N   2112         // zero range [0, GCNT_OFF+1600)
// fallback-chain scratch (disjoint from mono's region)
#define PART_OFF 4096         // [q(6)][r(50)][b(32)] = 9600
#define WEFF_OFF (4096+9600)  // [r(50)][ij(9)][t(8)] = 3600
#define WEFF_N   (REPN*72)

#define SEGH 7
#define NTASK 112             // 8 row-segments * 14 quad-cols
#define GRID_MONO 2048        // == B*C == 8 blocks/CU * 256 CU (full residency)

// ------------------------------------------------------------ weff compute
// Layout: [ij(9)][t(8)], t: 0..2 = Mh shifts, 3..5 = Mv shifts, 6 = Mid, 7 = 0.
__device__ __forceinline__ void weff_one(int idx,
        const float* __restrict__ w0, const float* __restrict__ w1,
        const int* __restrict__ Mh, const int* __restrict__ Mv,
        const int* __restrict__ Mid, float* __restrict__ ws)
{
    int r   = idx / 72;
    int rem = idx % 72;
    int ij  = rem >> 3;
    int t   = rem & 7;
    if (t == 7) { ws[WEFF_OFF + idx] = 0.f; return; }
    const int* M = (t < 3) ? (Mh + (t*REPN + r)*NKn)
                 : (t < 6) ? (Mv + ((t-3)*REPN + r)*NKn)
                           : (Mid + r*NKn);
    float acc = 0.f;
    #pragma unroll
    for (int k = 0; k < NKn; ++k)
        acc += (float)M[k] * (w0[(r*NKn + k)*9 + ij] + w1[(r*NKn + k)*9 + ij]);
    ws[WEFF_OFF + idx] = acc;
}

__global__ void k_weff(const float* __restrict__ w0, const float* __restrict__ w1,
                       const int* __restrict__ Mh, const int* __restrict__ Mv,
                       const int* __restrict__ Mid, float* __restrict__ ws)
{
    int idx = blockIdx.x * blockDim.x + threadIdx.x;
    if (idx < WEFF_N) weff_one(idx, w0, w1, Mh, Mv, Mid, ws);
}

// Zero the atomic accumulator/counter region (ws is poisoned between runs).
__global__ void k_init(float* __restrict__ ws)
{
    for (int i = threadIdx.x; i < INIT_N; i += 256) ws[i] = 0.f;
}

// Load input row `row` of channel ch as window X[0..7] = cols 4q-3..4q+4
// (zeros outside [0,56)). Also c55 = input[row][55] for q==0 lanes.
__device__ __forceinline__ void load_row8c(const float* __restrict__ ch, int row, int q,
                                           float* __restrict__ X, float& c55)
{
    bool rv = (row >= 0) && (row < Hn);
    int rc = rv ? row : 0;
    const float* rp = ch + rc*Wn;
    float4 c0 = *(const float4*)(rp + (q ? 4*q - 4 : 0));   // cols 4q-4..4q-1
    float4 c1 = *(const float4*)(rp + 4*q);                 // cols 4q..4q+3
    int ox = (4*q + 4 <= 55) ? 4*q + 4 : 55;                // clamp in-row
    float cx = rp[ox];
    float mr = rv ? 1.f : 0.f;
    float m0 = (rv && q > 0)  ? 1.f : 0.f;
    float mx = (rv && q < 13) ? 1.f : 0.f;
    X[0]=c0.y*m0; X[1]=c0.z*m0; X[2]=c0.w*m0;
    X[3]=c1.x*mr; X[4]=c1.y*mr; X[5]=c1.z*mr; X[6]=c1.w*mr;
    X[7]=cx*mx;
    c55 = (q == 0) ? rp[55]*mr : 0.f;
}

// ---------------------------------------------------- register-walk conv core
// Weights from LDS (swk, [ij][t] 8-padded). Per-row asm anti-LICM keeps the
// 63 weights out of long-lived registers (they'd spill at the 128-VGPR cap);
// reads are wave-uniform ds_read_b128 broadcasts, conflict-free.
template <typename F>
__device__ __forceinline__ void conv_walk(const float* __restrict__ ch,
        const float* __restrict__ swk, int tid, F emit)
{
    if (tid >= NTASK) return;
    int seg = tid / 14;
    int q   = tid - seg*14;
    int h0  = seg * SEGH;
    bool top = (seg == 0);

    float W[5][8], C[5], T[8];
    {
        float dummy;
        if (top) load_row8c(ch, 55, q, T, dummy);
    }
    #pragma unroll
    for (int k = 0; k < 5; ++k)
        load_row8c(ch, h0 - 3 + k, q, W[k], C[k]);

    #pragma unroll
    for (int s = 0; s < SEGH; ++s) {
        int h = h0 + s;
        float Wn8[8], Cn1;
        load_row8c(ch, h + 2, q, Wn8, Cn1);   // prefetch next row

        int z = 0;
        asm volatile("" : "+v"(z));           // defeat LICM: reload weights per row
        const float* wz = swk + z;

        float l1[4], l2[4], sm[4];
        #pragma unroll
        for (int p = 0; p < 4; ++p) { l1[p]=0.f; l2[p]=0.f; sm[p]=0.f; }
        #pragma unroll
        for (int i = 0; i < 3; ++i)
            #pragma unroll
            for (int j = 0; j < 3; ++j) {
                int ij = i*3 + j;
                float4 wa = *(const float4*)(wz + ij*8);      // t0..t3
                float4 wb = *(const float4*)(wz + ij*8 + 4);  // t4..t6,pad
                float wh0 = wa.x, wh1 = wa.y, wh2 = wa.z, wv0 = wa.w;
                float wv1 = wb.x, wv2 = wb.y, wid = wb.z;
                #pragma unroll
                for (int p = 0; p < 4; ++p) {
                    float a  = W[2+i][p+2+j];     // pos0
                    l1[p] = fmaf(a, wh0, l1[p]);
                    l2[p] = fmaf(a, wv0, l2[p]);
                    sm[p] = fmaf(a, wid, sm[p]);
                    float bA = W[1+i][p+j];       // posA
                    l1[p] = fmaf(bA, wh1, l1[p]);
                    l2[p] = fmaf(bA, wv2, l2[p]);
                    float bB = W[i][p+1+j];       // posB
                    l1[p] = fmaf(bB, wh2, l1[p]);
                    l2[p] = fmaf(bB, wv1, l2[p]);
                }
            }
        if (q == 0) {   // col wrap, pixel 0 only: t=1 (wh1), t=5 (wv2) at j=0
            #pragma unroll
            for (int i = 0; i < 3; ++i) {
                l1[0] = fmaf(C[1+i], wz[(3*i)*8 + 1], l1[0]);
                l2[0] = fmaf(C[1+i], wz[(3*i)*8 + 5], l2[0]);
            }
        }
        if (s == 0 && top) {   // row wrap, h==0 only: t=2 (wh2), t=4 (wv1) at i=0
            #pragma unroll
            for (int j = 0; j < 3; ++j)
                #pragma unroll
                for (int p = 0; p < 4; ++p) {
                    l1[p] = fmaf(T[p+1+j], wz[j*8 + 2], l1[p]);
                    l2[p] = fmaf(T[p+1+j], wz[j*8 + 4], l2[p]);
                }
        }
        float res[4] = {W[3][3], W[3][4], W[3][5], W[3][6]};
        emit(h, q, l1, l2, sm, res);

        #pragma unroll
        for (int k = 0; k < 4; ++k) {
            #pragma unroll
            for (int x = 0; x < 8; ++x) W[k][x] = W[k+1][x];
            C[k] = C[k+1];
        }
        #pragma unroll
        for (int x = 0; x < 8; ++x) W[4][x] = Wn8[x];
        C[4] = Cn1;
    }
}

// --------------------------------------------- monolithic capturable kernel
// Normal launch (graph-capturable — the cooperative launch never was, so the
// timed path has been the 3-kernel chain all along). No grid.sync:
//  * each rep block computes its OWN weff into LDS (63 tiny dots, L2-cached)
//  * cross-block sync is per-r only: 32 blocks atomicAdd 6 partial sums into
//    gsum[r] (device-scope), bump gcnt[r]; spin until 32 arrived. Safe: grid
//    2048 == 8 blocks/CU * 256 CU fully co-resident (gated host-side).
// __launch_bounds__(128,2) -> VGPR cap 128 (empirical: (128,2)->128, (128,4)
// ->64 and catastrophic spill, R1). 16 waves/CU.
__global__ void __launch_bounds__(128, 2) k_mono(const float* __restrict__ in,
        const float* __restrict__ w0, const float* __restrict__ w1,
        const int* __restrict__ Mh, const int* __restrict__ Mv,
        const int* __restrict__ Mid,
        const int* __restrict__ rep_idx, const int* __restrict__ ghost_idx,
        float* __restrict__ ws, float* __restrict__ out)
{
    int tid = threadIdx.x;
    int v = blockIdx.x;           // 0..2047
    int c = v & 63;
    int b = v >> 6;

    if (c >= REPN) {              // ghost: copy and retire
        int cin = ghost_idx[c - REPN];
        const float4* s4 = (const float4*)(in + ((size_t)(b*Cn + cin))*HWn);
        float4* d4 = (float4*)(out + ((size_t)(b*Cn + c))*HWn);
        for (int i = tid; i < HWn/4; i += 128) d4[i] = s4[i];
        return;
    }
    int r = c;

    __shared__ float swk[72];
    __shared__ float red[2][6];
    __shared__ float sred[6];

    // ---- per-block weff (redundant across b, trivially cheap, kills a sync)
    if (tid < 72) {
        int ij = tid >> 3, tt = tid & 7;
        if (tt == 7) swk[tid] = 0.f;
        else {
            const int* M = (tt < 3) ? (Mh + (tt*REPN + r)*NKn)
                         : (tt < 6) ? (Mv + ((tt-3)*REPN + r)*NKn)
                                    : (Mid + r*NKn);
            float acc = 0.f;
            #pragma unroll
            for (int k = 0; k < NKn; ++k)
                acc += (float)M[k] * (w0[(r*NKn + k)*9 + ij] + w1[(r*NKn + k)*9 + ij]);
            swk[tid] = acc;
        }
    }
    __syncthreads();

    const float* ch = in + ((size_t)(b*Cn + rep_idx[r]))*HWn;

    // ---- stats pass
    float s1=0.f,q1=0.f,s2=0.f,q2=0.f,s3=0.f,q3=0.f;
    conv_walk(ch, swk, tid,
        [&](int h, int q, float* l1, float* l2, float* sm, float* res) {
            (void)h; (void)q; (void)res;
            #pragma unroll
            for (int p = 0; p < 4; ++p) {
                s1 += l1[p]; q1 += l1[p]*l1[p];
                s2 += l2[p]; q2 += l2[p]*l2[p];
                s3 += sm[p]; q3 += sm[p]*sm[p];
            }
        });
    {
        float vals[6] = {s1,q1,s2,q2,s3,q3};
        int lane = tid & 63, wave = tid >> 6;
        #pragma unroll
        for (int x = 0; x < 6; ++x) {
            float y = vals[x];
            for (int o = 32; o; o >>= 1) y += __shfl_down(y, o, 64);
            if (lane == 0) red[wave][x] = y;
        }
    }
    __syncthreads();

    // ---- per-r accumulate + arrive (release) + spin (acquire)
    float* gsum = ws + GSUM_OFF + r*8;
    unsigned* gcnt = ((unsigned*)ws) + GCNT_OFF + r*32;
    if (tid < 6) {
        atomicAdd(&gsum[tid], red[0][tid] + red[1][tid]);
        __threadfence();          // drain + make adds visible before arrive
    }
    __syncthreads();
    if (tid == 0) {
        atomicAdd(gcnt, 1u);
        while (atomicAdd(gcnt, 0u) < (unsigned)Bn)
            __builtin_amdgcn_s_sleep(2);
    }
    __syncthreads();
    if (tid < 6) sred[tid] = atomicAdd(&gsum[tid], 0.f);   // coherent read
    __syncthreads();

    const float inv = 1.0f / NSTATf;
    float m1 = sred[0]*inv, v1 = sred[1]*inv - m1*m1;
    float m2 = sred[2]*inv, v2 = sred[3]*inv - m2*m2;
    float m3 = sred[4]*inv, v3 = sred[5]*inv - m3*m3;
    float r1 = rsqrtf(v1 + EPSf), r2 = rsqrtf(v2 + EPSf), r3 = rsqrtf(v3 + EPSf);

    float* dst = out + ((size_t)(b*Cn + c))*HWn;

    // ---- finalize pass (input L2-warm from stats pass)
    conv_walk(ch, swk, tid,
        [&](int h, int q, float* l1, float* l2, float* sm, float* res) {
            float4 o;
            o.x = (l1[0]-m1)*r1 + (l2[0]-m2)*r2 + (sm[0]-m3)*r3 + res[0];
            o.y = (l1[1]-m1)*r1 + (l2[1]-m2)*r2 + (sm[1]-m3)*r3 + res[1];
            o.z = (l1[2]-m1)*r1 + (l2[2]-m2)*r2 + (sm[2]-m3)*r3 + res[2];
            o.w = (l1[3]-m1)*r1 + (l2[3]-m2)*r2 + (sm[3]-m3)*r3 + res[3];
            *(float4*)(dst + h*Wn + 4*q) = o;
        });
}

// ------------------------------------- fallback kernels (proven chain)
__global__ void __launch_bounds__(128) k_stats(const float* __restrict__ in,
        const int* __restrict__ rep_idx, float* __restrict__ ws)
{
    int bid = blockIdx.x;
    int r = bid % REPN;
    int b = bid / REPN;
    int tid = threadIdx.x;

    __shared__ float swk[72];
    if (tid < 72) swk[tid] = ws[WEFF_OFF + r*72 + tid];
    __syncthreads();
    const float* ch = in + ((size_t)(b*Cn + rep_idx[r]))*HWn;

    float s1=0.f,q1=0.f,s2=0.f,q2=0.f,s3=0.f,q3=0.f;
    conv_walk(ch, swk, tid,
        [&](int h, int q, float* l1, float* l2, float* sm, float* res) {
            (void)h; (void)q; (void)res;
            #pragma unroll
            for (int p = 0; p < 4; ++p) {
                s1 += l1[p]; q1 += l1[p]*l1[p];
                s2 += l2[p]; q2 += l2[p]*l2[p];
                s3 += sm[p]; q3 += sm[p]*sm[p];
            }
        });

    __shared__ float red[2][6];
    float vals[6] = {s1,q1,s2,q2,s3,q3};
    int lane = tid & 63, wave = tid >> 6;
    #pragma unroll
    for (int v = 0; v < 6; ++v) {
        float x = vals[v];
        for (int o = 32; o; o >>= 1) x += __shfl_down(x, o, 64);
        if (lane == 0) red[wave][v] = x;
    }
    __syncthreads();
    if (tid < 6)
        ws[PART_OFF + (tid*REPN + r)*Bn + b] = red[0][tid] + red[1][tid];
}

__global__ void __launch_bounds__(128) k_out(const float* __restrict__ in,
        const int* __restrict__ rep_idx, const int* __restrict__ ghost_idx,
        const float* __restrict__ ws, float* __restrict__ out)
{
    int bid = blockIdx.x;
    int c = bid % Cn;
    int b = bid / Cn;
    int tid = threadIdx.x;

    if (c >= REPN) {
        int cin = ghost_idx[c - REPN];
        const float4* s4 = (const float4*)(in + ((size_t)(b*Cn + cin))*HWn);
        float4* d4 = (float4*)(out + ((size_t)(b*Cn + c))*HWn);
        for (int i = tid; i < HWn/4; i += 128) d4[i] = s4[i];
        return;
    }

    int r = c;
    __shared__ float swk[72];
    __shared__ float sred[6];
    if (tid < 72) swk[tid] = ws[WEFF_OFF + r*72 + tid];
    if (tid < 6) {
        const float* pp = ws + PART_OFF + (tid*REPN + r)*Bn;
        float s = 0.f;
        #pragma unroll
        for (int i = 0; i < Bn; ++i) s += pp[i];
        sred[tid] = s;
    }
    __syncthreads();
    const float inv = 1.0f / NSTATf;
    float m1 = sred[0]*inv, v1 = sred[1]*inv - m1*m1;
    float m2 = sred[2]*inv, v2 = sred[3]*inv - m2*m2;
    float m3 = sred[4]*inv, v3 = sred[5]*inv - m3*m3;
    float r1 = rsqrtf(v1 + EPSf), r2 = rsqrtf(v2 + EPSf), r3 = rsqrtf(v3 + EPSf);

    const float* ch = in + ((size_t)(b*Cn + rep_idx[r]))*HWn;
    float* dst = out + ((size_t)(b*Cn + c))*HWn;

    conv_walk(ch, swk, tid,
        [&](int h, int q, float* l1, float* l2, float* sm, float* res) {
            float4 o;
            o.x = (l1[0]-m1)*r1 + (l2[0]-m2)*r2 + (sm[0]-m3)*r3 + res[0];
            o.y = (l1[1]-m1)*r1 + (l2[1]-m2)*r2 + (sm[1]-m3)*r3 + res[1];
            o.z = (l1[2]-m1)*r1 + (l2[2]-m2)*r2 + (sm[2]-m3)*r3 + res[2];
            o.w = (l1[3]-m1)*r1 + (l2[3]-m2)*r2 + (sm[3]-m3)*r3 + res[3];
            *(float4*)(dst + h*Wn + 4*q) = o;
        });
}

extern "C" void kernel_launch(void* const* d_in, const int* in_sizes, int n_in,
                              void* d_out, int out_size, void* d_ws, size_t ws_size,
                              hipStream_t stream) {
    const float* in   = (const float*)d_in[0];
    const float* w0   = (const float*)d_in[1];
    const float* w1   = (const float*)d_in[2];
    const int*   Mh   = (const int*)d_in[3];
    const int*   Mv   = (const int*)d_in[4];
    const int*   Mid  = (const int*)d_in[5];
    const int*   ghost= (const int*)d_in[6];
    const int*   rep  = (const int*)d_in[7];
    float* out  = (float*)d_out;
    float* ws   = (float*)d_ws;

    // Deadlock gate: the mono kernel's per-r spin needs all 2048 blocks
    // co-resident -> 8 blocks/CU on 256 CUs. Host-side query, capture-safe.
    int maxBlk = 0;
    hipError_t qerr = hipOccupancyMaxActiveBlocksPerMultiprocessor(
        &maxBlk, (const void*)k_mono, 128, 0);
    bool mono_ok = (qerr == hipSuccess) && (maxBlk >= 8);

    if (mono_ok) {
        k_init<<<1, 256, 0, stream>>>(ws);
        k_mono<<<GRID_MONO, 128, 0, stream>>>(in, w0, w1, Mh, Mv, Mid,
                                              rep, ghost, ws, out);
        return;
    }
    // Fallback: proven 3-kernel chain
    k_weff<<<(WEFF_N + 127)/128, 128, 0, stream>>>(w0, w1, Mh, Mv, Mid, ws);
    k_stats<<<Bn*REPN, 128, 0, stream>>>(in, rep, ws);
    k_out<<<Bn*Cn, 128, 0, stream>>>(in, rep, ghost, ws, out);
}

// Round 5
// 121.371 us; speedup vs baseline: 1.1103x; 1.1075x over previous
//
#include <hip/hip_runtime.h>

#define Bn 32
#define Cn 64
#define Hn 56
#define Wn 56
#define REPN 50
#define NKn 17
#define HWn (Hn*Wn)           // 3136
#define NSTATf 100352.0f      // B*H*W
#define EPSf 1e-5f

// ws layout (floats): only stats partials now. Every slot is written by
// k_pass1 before k_pass2 reads it (ws is poisoned between iterations).
#define PART_OFF 0            // [stat(6)][r(50)][b(32)] = 9600

#define SEGH 7
#define NTASK 112             // 8 row-segments * 14 quad-cols

// ---------------------------------------------------------------- weff in LDS
// swk layout t-major: swk[t*9+ij]; t: 0..2 Mh shifts, 3..5 Mv shifts, 6 Mid.
__device__ __forceinline__ void block_weff(int r, int tid,
        const float* __restrict__ w0, const float* __restrict__ w1,
        const int* __restrict__ Mh, const int* __restrict__ Mv,
        const int* __restrict__ Mid, float* __restrict__ swk)
{
    if (tid < 63) {
        int t = tid / 9, ij = tid - t*9;
        const int* M = (t < 3) ? (Mh + (t*REPN + r)*NKn)
                     : (t < 6) ? (Mv + ((t-3)*REPN + r)*NKn)
                               : (Mid + r*NKn);
        float acc = 0.f;
        #pragma unroll
        for (int k = 0; k < NKn; ++k)
            acc += (float)M[k] * (w0[(r*NKn + k)*9 + ij] + w1[(r*NKn + k)*9 + ij]);
        swk[t*9 + ij] = acc;
    }
}

// Load input row `row` of channel ch as window X[0..7] = cols 4q-3..4q+4
// (zeros outside [0,56)). Also c55 = input[row][55] for q==0 lanes.
__device__ __forceinline__ void load_row8c(const float* __restrict__ ch, int row, int q,
                                           float* __restrict__ X, float& c55)
{
    bool rv = (row >= 0) && (row < Hn);
    int rc = rv ? row : 0;
    const float* rp = ch + rc*Wn;
    float4 c0 = *(const float4*)(rp + (q ? 4*q - 4 : 0));   // cols 4q-4..4q-1
    float4 c1 = *(const float4*)(rp + 4*q);                 // cols 4q..4q+3
    int ox = (4*q + 4 <= 55) ? 4*q + 4 : 55;                // clamp in-row
    float cx = rp[ox];
    float mr = rv ? 1.f : 0.f;
    float m0 = (rv && q > 0)  ? 1.f : 0.f;
    float mx = (rv && q < 13) ? 1.f : 0.f;
    X[0]=c0.y*m0; X[1]=c0.z*m0; X[2]=c0.w*m0;
    X[3]=c1.x*mr; X[4]=c1.y*mr; X[5]=c1.z*mr; X[6]=c1.w*mr;
    X[7]=cx*mx;
    c55 = (q == 0) ? rp[55]*mr : 0.f;
}

// -------------------------------------------- 3-accumulator walk (stats pass)
// Register weights wk[63], t-major (R0-proven core): wh0=wk[ij], wh1=wk[9+ij],
// wh2=wk[18+ij], wv0=wk[27+ij], wv1=wk[36+ij], wv2=wk[45+ij], wid=wk[54+ij].
template <typename F>
__device__ __forceinline__ void conv_walk3(const float* __restrict__ ch,
        const float (&wk)[63], int tid, F emit)
{
    if (tid >= NTASK) return;
    int seg = tid / 14;
    int q   = tid - seg*14;
    int h0  = seg * SEGH;
    bool top = (seg == 0);

    float W[5][8], C[5], T[8];
    {
        float dummy;
        if (top) load_row8c(ch, 55, q, T, dummy);
    }
    #pragma unroll
    for (int k = 0; k < 5; ++k)
        load_row8c(ch, h0 - 3 + k, q, W[k], C[k]);

    #pragma unroll
    for (int s = 0; s < SEGH; ++s) {
        int h = h0 + s;
        float Wn8[8], Cn1;
        load_row8c(ch, h + 2, q, Wn8, Cn1);   // prefetch next row

        float l1[4], l2[4], sm[4];
        #pragma unroll
        for (int p = 0; p < 4; ++p) { l1[p]=0.f; l2[p]=0.f; sm[p]=0.f; }
        #pragma unroll
        for (int i = 0; i < 3; ++i)
            #pragma unroll
            for (int j = 0; j < 3; ++j) {
                int ij = i*3 + j;
                float wh0 = wk[ij],    wh1 = wk[9+ij],  wh2 = wk[18+ij];
                float wv0 = wk[27+ij], wv1 = wk[36+ij], wv2 = wk[45+ij];
                float wid = wk[54+ij];
                #pragma unroll
                for (int p = 0; p < 4; ++p) {
                    float a  = W[2+i][p+2+j];     // pos0
                    l1[p] = fmaf(a, wh0, l1[p]);
                    l2[p] = fmaf(a, wv0, l2[p]);
                    sm[p] = fmaf(a, wid, sm[p]);
                    float bA = W[1+i][p+j];       // posA
                    l1[p] = fmaf(bA, wh1, l1[p]);
                    l2[p] = fmaf(bA, wv2, l2[p]);
                    float bB = W[i][p+1+j];       // posB
                    l1[p] = fmaf(bB, wh2, l1[p]);
                    l2[p] = fmaf(bB, wv1, l2[p]);
                }
            }
        if (q == 0) {   // col wrap, pixel 0: posA j=0 -> t1 (l1), t5 (l2)
            #pragma unroll
            for (int i = 0; i < 3; ++i) {
                l1[0] = fmaf(C[1+i], wk[9+3*i],  l1[0]);
                l2[0] = fmaf(C[1+i], wk[45+3*i], l2[0]);
            }
        }
        if (s == 0 && top) {   // row wrap, h==0: posB i=0 -> t2 (l1), t4 (l2)
            #pragma unroll
            for (int j = 0; j < 3; ++j)
                #pragma unroll
                for (int p = 0; p < 4; ++p) {
                    l1[p] = fmaf(T[p+1+j], wk[18+j], l1[p]);
                    l2[p] = fmaf(T[p+1+j], wk[36+j], l2[p]);
                }
        }
        float res[4] = {W[3][3], W[3][4], W[3][5], W[3][6]};
        emit(h, q, l1, l2, sm, res);

        #pragma unroll
        for (int k = 0; k < 4; ++k) {
            #pragma unroll
            for (int x = 0; x < 8; ++x) W[k][x] = W[k+1][x];
            C[k] = C[k+1];
        }
        #pragma unroll
        for (int x = 0; x < 8; ++x) W[4][x] = Wn8[x];
        C[4] = Cn1;
    }
}

// ------------------------------- single-accumulator walk (BN-folded output)
// cw0[ij] = r1*wh0 + r2*wv0 + r3*wid   (pos0, includes sm path)
// cwA[ij] = r1*wh1 + r2*wv2            (posA)
// cwB[ij] = r1*wh2 + r2*wv1            (posB)
// out = conv(cw) - K + res, K = m1*r1 + m2*r2 + m3*r3. 27 FMA/px vs 63.
__device__ __forceinline__ void conv_walk1(const float* __restrict__ ch,
        const float (&cw0)[9], const float (&cwA)[9], const float (&cwB)[9],
        float Kc, int tid, float* __restrict__ dst)
{
    if (tid >= NTASK) return;
    int seg = tid / 14;
    int q   = tid - seg*14;
    int h0  = seg * SEGH;
    bool top = (seg == 0);

    float W[5][8], C[5], T[8];
    {
        float dummy;
        if (top) load_row8c(ch, 55, q, T, dummy);
    }
    #pragma unroll
    for (int k = 0; k < 5; ++k)
        load_row8c(ch, h0 - 3 + k, q, W[k], C[k]);

    #pragma unroll
    for (int s = 0; s < SEGH; ++s) {
        int h = h0 + s;
        float Wn8[8], Cn1;
        load_row8c(ch, h + 2, q, Wn8, Cn1);   // prefetch next row

        float acc[4];
        #pragma unroll
        for (int p = 0; p < 4; ++p) acc[p] = 0.f;
        #pragma unroll
        for (int i = 0; i < 3; ++i)
            #pragma unroll
            for (int j = 0; j < 3; ++j) {
                int ij = i*3 + j;
                float w0c = cw0[ij], wAc = cwA[ij], wBc = cwB[ij];
                #pragma unroll
                for (int p = 0; p < 4; ++p) {
                    acc[p] = fmaf(W[2+i][p+2+j], w0c, acc[p]);   // pos0
                    acc[p] = fmaf(W[1+i][p+j],   wAc, acc[p]);   // posA
                    acc[p] = fmaf(W[i][p+1+j],   wBc, acc[p]);   // posB
                }
            }
        if (q == 0) {   // col wrap, pixel 0: posA j=0
            #pragma unroll
            for (int i = 0; i < 3; ++i)
                acc[0] = fmaf(C[1+i], cwA[3*i], acc[0]);
        }
        if (s == 0 && top) {   // row wrap, h==0: posB i=0
            #pragma unroll
            for (int j = 0; j < 3; ++j)
                #pragma unroll
                for (int p = 0; p < 4; ++p)
                    acc[p] = fmaf(T[p+1+j], cwB[j], acc[p]);
        }
        float4 o;
        o.x = acc[0] - Kc + W[3][3];
        o.y = acc[1] - Kc + W[3][4];
        o.z = acc[2] - Kc + W[3][5];
        o.w = acc[3] - Kc + W[3][6];
        *(float4*)(dst + h*Wn + 4*q) = o;

        #pragma unroll
        for (int k = 0; k < 4; ++k) {
            #pragma unroll
            for (int x = 0; x < 8; ++x) W[k][x] = W[k+1][x];
            C[k] = C[k+1];
        }
        #pragma unroll
        for (int x = 0; x < 8; ++x) W[4][x] = Wn8[x];
        C[4] = Cn1;
    }
}

// ------------------------------------------------------- pass 1: stats
// One block per (r,b). Per-block weff (LDS) -> one-time register copy ->
// 3-accumulator conv -> wave-shuffle reduce -> 6 partials to ws.
__global__ void __launch_bounds__(128) k_pass1(const float* __restrict__ in,
        const float* __restrict__ w0, const float* __restrict__ w1,
        const int* __restrict__ Mh, const int* __restrict__ Mv,
        const int* __restrict__ Mid,
        const int* __restrict__ rep_idx, float* __restrict__ ws)
{
    int bid = blockIdx.x;
    int r = bid % REPN;
    int b = bid / REPN;
    int tid = threadIdx.x;

    __shared__ float swk[63];
    __shared__ float red[2][6];

    block_weff(r, tid, w0, w1, Mh, Mv, Mid, swk);
    __syncthreads();
    float wk[63];
    #pragma unroll
    for (int i = 0; i < 63; ++i) wk[i] = swk[i];

    const float* ch = in + ((size_t)(b*Cn + rep_idx[r]))*HWn;

    float s1=0.f,q1=0.f,s2=0.f,q2=0.f,s3=0.f,q3=0.f;
    conv_walk3(ch, wk, tid,
        [&](int h, int q, float* l1, float* l2, float* sm, float* res) {
            (void)h; (void)q; (void)res;
            #pragma unroll
            for (int p = 0; p < 4; ++p) {
                s1 += l1[p]; q1 += l1[p]*l1[p];
                s2 += l2[p]; q2 += l2[p]*l2[p];
                s3 += sm[p]; q3 += sm[p]*sm[p];
            }
        });

    float vals[6] = {s1,q1,s2,q2,s3,q3};
    int lane = tid & 63, wave = tid >> 6;
    #pragma unroll
    for (int x = 0; x < 6; ++x) {
        float y = vals[x];
        for (int o = 32; o; o >>= 1) y += __shfl_down(y, o, 64);
        if (lane == 0) red[wave][x] = y;
    }
    __syncthreads();
    if (tid < 6)
        ws[PART_OFF + (tid*REPN + r)*Bn + b] = red[0][tid] + red[1][tid];
}

// ------------------------------------------------ pass 2: finalize + output
// One block per (b,c). Ghost: copy. Rep: weff (tid<63) || partial-reduce
// (tid 64..69) in parallel, fold BN scales into 27 combined register weights,
// single-accumulator conv, write.
__global__ void __launch_bounds__(128) k_pass2(const float* __restrict__ in,
        const float* __restrict__ w0, const float* __restrict__ w1,
        const int* __restrict__ Mh, const int* __restrict__ Mv,
        const int* __restrict__ Mid,
        const int* __restrict__ rep_idx, const int* __restrict__ ghost_idx,
        const float* __restrict__ ws, float* __restrict__ out)
{
    int bid = blockIdx.x;
    int c = bid & 63;
    int b = bid >> 6;
    int tid = threadIdx.x;

    if (c >= REPN) {              // ghost: copy and retire (block-uniform)
        int cin = ghost_idx[c - REPN];
        const float4* s4 = (const float4*)(in + ((size_t)(b*Cn + cin))*HWn);
        float4* d4 = (float4*)(out + ((size_t)(b*Cn + c))*HWn);
        for (int i = tid; i < HWn/4; i += 128) d4[i] = s4[i];
        return;
    }
    int r = c;

    __shared__ float swk[63];
    __shared__ float sred[6];

    block_weff(r, tid, w0, w1, Mh, Mv, Mid, swk);       // tid < 63
    if (tid >= 64 && tid < 70) {                        // wave 1: reduce partials
        int x = tid - 64;
        const float* pp = ws + PART_OFF + (x*REPN + r)*Bn;
        float s = 0.f;
        #pragma unroll
        for (int i = 0; i < Bn; ++i) s += pp[i];
        sred[x] = s;
    }
    __syncthreads();

    const float inv = 1.0f / NSTATf;
    float m1 = sred[0]*inv, v1 = sred[1]*inv - m1*m1;
    float m2 = sred[2]*inv, v2 = sred[3]*inv - m2*m2;
    float m3 = sred[4]*inv, v3 = sred[5]*inv - m3*m3;
    float r1 = rsqrtf(v1 + EPSf), r2 = rsqrtf(v2 + EPSf), r3 = rsqrtf(v3 + EPSf);
    float Kc = m1*r1 + m2*r2 + m3*r3;

    float cw0[9], cwA[9], cwB[9];
    #pragma unroll
    for (int ij = 0; ij < 9; ++ij) {
        cw0[ij] = r1*swk[ij]      + r2*swk[27+ij] + r3*swk[54+ij];
        cwA[ij] = r1*swk[9+ij]    + r2*swk[45+ij];
        cwB[ij] = r1*swk[18+ij]   + r2*swk[36+ij];
    }

    const float* ch = in + ((size_t)(b*Cn + rep_idx[r]))*HWn;
    float* dst = out + ((size_t)(b*Cn + c))*HWn;
    conv_walk1(ch, cw0, cwA, cwB, Kc, tid, dst);
}

extern "C" void kernel_launch(void* const* d_in, const int* in_sizes, int n_in,
                              void* d_out, int out_size, void* d_ws, size_t ws_size,
                              hipStream_t stream) {
    const float* in   = (const float*)d_in[0];
    const float* w0   = (const float*)d_in[1];
    const float* w1   = (const float*)d_in[2];
    const int*   Mh   = (const int*)d_in[3];
    const int*   Mv   = (const int*)d_in[4];
    const int*   Mid  = (const int*)d_in[5];
    const int*   ghost= (const int*)d_in[6];
    const int*   rep  = (const int*)d_in[7];
    float* out  = (float*)d_out;
    float* ws   = (float*)d_ws;

    // Plain 2-kernel chain: graph-capturable, no gates, no cross-block sync.
    k_pass1<<<REPN*Bn, 128, 0, stream>>>(in, w0, w1, Mh, Mv, Mid, rep, ws);
    k_pass2<<<Bn*Cn,   128, 0, stream>>>(in, w0, w1, Mh, Mv, Mid, rep, ghost, ws, out);
}

// Round 6
// 119.675 us; speedup vs baseline: 1.1261x; 1.0142x over previous
//
#include <hip/hip_runtime.h>

#define Bn 32
#define Cn 64
#define Hn 56
#define Wn 56
#define REPN 50
#define NKn 17
#define HWn (Hn*Wn)           // 3136
#define NSTATf 100352.0f      // B*H*W
#define EPSf 1e-5f

// ws layout (floats): only stats partials. Every slot is written by
// k_pass1 before k_pass2 reads it (ws is poisoned between iterations).
#define PART_OFF 0            // [stat(6)][r(50)][b(32)] = 9600

#define SEGH 7
#define NTASK 112             // 8 row-segments * 14 quad-cols

// ---------------------------------------------------------------- weff in LDS
// swk layout t-major: swk[t*9+ij]; t: 0..2 Mh shifts, 3..5 Mv shifts, 6 Mid.
__device__ __forceinline__ void block_weff(int r, int tid,
        const float* __restrict__ w0, const float* __restrict__ w1,
        const int* __restrict__ Mh, const int* __restrict__ Mv,
        const int* __restrict__ Mid, float* __restrict__ swk)
{
    if (tid < 63) {
        int t = tid / 9, ij = tid - t*9;
        const int* M = (t < 3) ? (Mh + (t*REPN + r)*NKn)
                     : (t < 6) ? (Mv + ((t-3)*REPN + r)*NKn)
                               : (Mid + r*NKn);
        float acc = 0.f;
        #pragma unroll
        for (int k = 0; k < NKn; ++k)
            acc += (float)M[k] * (w0[(r*NKn + k)*9 + ij] + w1[(r*NKn + k)*9 + ij]);
        swk[t*9 + ij] = acc;
    }
}

// Load input row `row` of channel ch as window X[0..7] = cols 4q-3..4q+4
// (zeros outside [0,56)). Also c55 = input[row][55] for q==0 lanes.
__device__ __forceinline__ void load_row8c(const float* __restrict__ ch, int row, int q,
                                           float* __restrict__ X, float& c55)
{
    bool rv = (row >= 0) && (row < Hn);
    int rc = rv ? row : 0;
    const float* rp = ch + rc*Wn;
    float4 c0 = *(const float4*)(rp + (q ? 4*q - 4 : 0));   // cols 4q-4..4q-1
    float4 c1 = *(const float4*)(rp + 4*q);                 // cols 4q..4q+3
    int ox = (4*q + 4 <= 55) ? 4*q + 4 : 55;                // clamp in-row
    float cx = rp[ox];
    float mr = rv ? 1.f : 0.f;
    float m0 = (rv && q > 0)  ? 1.f : 0.f;
    float mx = (rv && q < 13) ? 1.f : 0.f;
    X[0]=c0.y*m0; X[1]=c0.z*m0; X[2]=c0.w*m0;
    X[3]=c1.x*mr; X[4]=c1.y*mr; X[5]=c1.z*mr; X[6]=c1.w*mr;
    X[7]=cx*mx;
    c55 = (q == 0) ? rp[55]*mr : 0.f;
}

// -------------------------------------------- 3-accumulator walk (stats pass)
// 6-row rolling window: rows h-3..h+2 resident, prefetch row h+3 at iter s,
// consumed at iter s+2 -> ~2 iterations (~1200 cyc at 3 waves/SIMD) of hiding
// for the ~900-cyc cold-HBM latency (the harness's 256MB poison fill flushes
// L3 between iterations, so pass-1 input reads are HBM-cold).
// Register weights wk[63], t-major: wh0=wk[ij], wh1=wk[9+ij], wh2=wk[18+ij],
// wv0=wk[27+ij], wv1=wk[36+ij], wv2=wk[45+ij], wid=wk[54+ij].
template <typename F>
__device__ __forceinline__ void conv_walk3(const float* __restrict__ ch,
        const float (&wk)[63], int tid, F emit)
{
    if (tid >= NTASK) return;
    int seg = tid / 14;
    int q   = tid - seg*14;
    int h0  = seg * SEGH;
    bool top = (seg == 0);

    float W[6][8], C[6], T[8];
    {
        float dummy;
        if (top) load_row8c(ch, 55, q, T, dummy);
    }
    #pragma unroll
    for (int k = 0; k < 6; ++k)
        load_row8c(ch, h0 - 3 + k, q, W[k], C[k]);

    #pragma unroll
    for (int s = 0; s < SEGH; ++s) {
        int h = h0 + s;
        float Wn8[8], Cn1;
        load_row8c(ch, h + 3, q, Wn8, Cn1);   // prefetch 2 rows ahead

        float l1[4], l2[4], sm[4];
        #pragma unroll
        for (int p = 0; p < 4; ++p) { l1[p]=0.f; l2[p]=0.f; sm[p]=0.f; }
        #pragma unroll
        for (int i = 0; i < 3; ++i)
            #pragma unroll
            for (int j = 0; j < 3; ++j) {
                int ij = i*3 + j;
                float wh0 = wk[ij],    wh1 = wk[9+ij],  wh2 = wk[18+ij];
                float wv0 = wk[27+ij], wv1 = wk[36+ij], wv2 = wk[45+ij];
                float wid = wk[54+ij];
                #pragma unroll
                for (int p = 0; p < 4; ++p) {
                    float a  = W[2+i][p+2+j];     // pos0 (rows h-1..h+1)
                    l1[p] = fmaf(a, wh0, l1[p]);
                    l2[p] = fmaf(a, wv0, l2[p]);
                    sm[p] = fmaf(a, wid, sm[p]);
                    float bA = W[1+i][p+j];       // posA (rows h-2..h)
                    l1[p] = fmaf(bA, wh1, l1[p]);
                    l2[p] = fmaf(bA, wv2, l2[p]);
                    float bB = W[i][p+1+j];       // posB (rows h-3..h-1)
                    l1[p] = fmaf(bB, wh2, l1[p]);
                    l2[p] = fmaf(bB, wv1, l2[p]);
                }
            }
        if (q == 0) {   // col wrap, pixel 0: posA j=0 -> t1 (l1), t5 (l2)
            #pragma unroll
            for (int i = 0; i < 3; ++i) {
                l1[0] = fmaf(C[1+i], wk[9+3*i],  l1[0]);
                l2[0] = fmaf(C[1+i], wk[45+3*i], l2[0]);
            }
        }
        if (s == 0 && top) {   // row wrap, h==0: posB i=0 -> t2 (l1), t4 (l2)
            #pragma unroll
            for (int j = 0; j < 3; ++j)
                #pragma unroll
                for (int p = 0; p < 4; ++p) {
                    l1[p] = fmaf(T[p+1+j], wk[18+j], l1[p]);
                    l2[p] = fmaf(T[p+1+j], wk[36+j], l2[p]);
                }
        }
        float res[4] = {W[3][3], W[3][4], W[3][5], W[3][6]};
        emit(h, q, l1, l2, sm, res);

        #pragma unroll
        for (int k = 0; k < 5; ++k) {
            #pragma unroll
            for (int x = 0; x < 8; ++x) W[k][x] = W[k+1][x];
            C[k] = C[k+1];
        }
        #pragma unroll
        for (int x = 0; x < 8; ++x) W[5][x] = Wn8[x];
        C[5] = Cn1;
    }
}

// ------------------------------- single-accumulator walk (BN-folded output)
// cw0[ij] = r1*wh0 + r2*wv0 + r3*wid   (pos0, includes sm path)
// cwA[ij] = r1*wh1 + r2*wv2            (posA)
// cwB[ij] = r1*wh2 + r2*wv1            (posB)
// out = conv(cw) - K + res, K = m1*r1 + m2*r2 + m3*r3. 27 FMA/px vs 63.
// Same 6-row window / 2-deep prefetch as conv_walk3.
__device__ __forceinline__ void conv_walk1(const float* __restrict__ ch,
        const float (&cw0)[9], const float (&cwA)[9], const float (&cwB)[9],
        float Kc, int tid, float* __restrict__ dst)
{
    if (tid >= NTASK) return;
    int seg = tid / 14;
    int q   = tid - seg*14;
    int h0  = seg * SEGH;
    bool top = (seg == 0);

    float W[6][8], C[6], T[8];
    {
        float dummy;
        if (top) load_row8c(ch, 55, q, T, dummy);
    }
    #pragma unroll
    for (int k = 0; k < 6; ++k)
        load_row8c(ch, h0 - 3 + k, q, W[k], C[k]);

    #pragma unroll
    for (int s = 0; s < SEGH; ++s) {
        int h = h0 + s;
        float Wn8[8], Cn1;
        load_row8c(ch, h + 3, q, Wn8, Cn1);   // prefetch 2 rows ahead

        float acc[4];
        #pragma unroll
        for (int p = 0; p < 4; ++p) acc[p] = 0.f;
        #pragma unroll
        for (int i = 0; i < 3; ++i)
            #pragma unroll
            for (int j = 0; j < 3; ++j) {
                int ij = i*3 + j;
                float w0c = cw0[ij], wAc = cwA[ij], wBc = cwB[ij];
                #pragma unroll
                for (int p = 0; p < 4; ++p) {
                    acc[p] = fmaf(W[2+i][p+2+j], w0c, acc[p]);   // pos0
                    acc[p] = fmaf(W[1+i][p+j],   wAc, acc[p]);   // posA
                    acc[p] = fmaf(W[i][p+1+j],   wBc, acc[p]);   // posB
                }
            }
        if (q == 0) {   // col wrap, pixel 0: posA j=0
            #pragma unroll
            for (int i = 0; i < 3; ++i)
                acc[0] = fmaf(C[1+i], cwA[3*i], acc[0]);
        }
        if (s == 0 && top) {   // row wrap, h==0: posB i=0
            #pragma unroll
            for (int j = 0; j < 3; ++j)
                #pragma unroll
                for (int p = 0; p < 4; ++p)
                    acc[p] = fmaf(T[p+1+j], cwB[j], acc[p]);
        }
        float4 o;
        o.x = acc[0] - Kc + W[3][3];
        o.y = acc[1] - Kc + W[3][4];
        o.z = acc[2] - Kc + W[3][5];
        o.w = acc[3] - Kc + W[3][6];
        *(float4*)(dst + h*Wn + 4*q) = o;

        #pragma unroll
        for (int k = 0; k < 5; ++k) {
            #pragma unroll
            for (int x = 0; x < 8; ++x) W[k][x] = W[k+1][x];
            C[k] = C[k+1];
        }
        #pragma unroll
        for (int x = 0; x < 8; ++x) W[5][x] = Wn8[x];
        C[5] = Cn1;
    }
}

// ------------------------------------------------------- pass 1: stats
// One block per (r,b). Per-block weff (LDS) -> one-time register copy ->
// 3-accumulator conv -> wave-shuffle reduce -> 6 partials to ws.
__global__ void __launch_bounds__(128) k_pass1(const float* __restrict__ in,
        const float* __restrict__ w0, const float* __restrict__ w1,
        const int* __restrict__ Mh, const int* __restrict__ Mv,
        const int* __restrict__ Mid,
        const int* __restrict__ rep_idx, float* __restrict__ ws)
{
    int bid = blockIdx.x;
    int r = bid % REPN;
    int b = bid / REPN;
    int tid = threadIdx.x;

    __shared__ float swk[63];
    __shared__ float red[2][6];

    block_weff(r, tid, w0, w1, Mh, Mv, Mid, swk);
    __syncthreads();
    float wk[63];
    #pragma unroll
    for (int i = 0; i < 63; ++i) wk[i] = swk[i];

    const float* ch = in + ((size_t)(b*Cn + rep_idx[r]))*HWn;

    float s1=0.f,q1=0.f,s2=0.f,q2=0.f,s3=0.f,q3=0.f;
    conv_walk3(ch, wk, tid,
        [&](int h, int q, float* l1, float* l2, float* sm, float* res) {
            (void)h; (void)q; (void)res;
            #pragma unroll
            for (int p = 0; p < 4; ++p) {
                s1 += l1[p]; q1 += l1[p]*l1[p];
                s2 += l2[p]; q2 += l2[p]*l2[p];
                s3 += sm[p]; q3 += sm[p]*sm[p];
            }
        });

    float vals[6] = {s1,q1,s2,q2,s3,q3};
    int lane = tid & 63, wave = tid >> 6;
    #pragma unroll
    for (int x = 0; x < 6; ++x) {
        float y = vals[x];
        for (int o = 32; o; o >>= 1) y += __shfl_down(y, o, 64);
        if (lane == 0) red[wave][x] = y;
    }
    __syncthreads();
    if (tid < 6)
        ws[PART_OFF + (tid*REPN + r)*Bn + b] = red[0][tid] + red[1][tid];
}

// ------------------------------------------------ pass 2: finalize + output
// One block per (b,c). Ghost: copy. Rep: weff (tid<63) || partial-reduce
// (tid 64..69) in parallel, fold BN scales into 27 combined register weights,
// single-accumulator conv, write.
__global__ void __launch_bounds__(128) k_pass2(const float* __restrict__ in,
        const float* __restrict__ w0, const float* __restrict__ w1,
        const int* __restrict__ Mh, const int* __restrict__ Mv,
        const int* __restrict__ Mid,
        const int* __restrict__ rep_idx, const int* __restrict__ ghost_idx,
        const float* __restrict__ ws, float* __restrict__ out)
{
    int bid = blockIdx.x;
    int c = bid & 63;
    int b = bid >> 6;
    int tid = threadIdx.x;

    if (c >= REPN) {              // ghost: copy and retire (block-uniform)
        int cin = ghost_idx[c - REPN];
        const float4* s4 = (const float4*)(in + ((size_t)(b*Cn + cin))*HWn);
        float4* d4 = (float4*)(out + ((size_t)(b*Cn + c))*HWn);
        for (int i = tid; i < HWn/4; i += 128) d4[i] = s4[i];
        return;
    }
    int r = c;

    __shared__ float swk[63];
    __shared__ float sred[6];

    block_weff(r, tid, w0, w1, Mh, Mv, Mid, swk);       // tid < 63
    if (tid >= 64 && tid < 70) {                        // wave 1: reduce partials
        int x = tid - 64;
        const float* pp = ws + PART_OFF + (x*REPN + r)*Bn;
        float s = 0.f;
        #pragma unroll
        for (int i = 0; i < Bn; ++i) s += pp[i];
        sred[x] = s;
    }
    __syncthreads();

    const float inv = 1.0f / NSTATf;
    float m1 = sred[0]*inv, v1 = sred[1]*inv - m1*m1;
    float m2 = sred[2]*inv, v2 = sred[3]*inv - m2*m2;
    float m3 = sred[4]*inv, v3 = sred[5]*inv - m3*m3;
    float r1 = rsqrtf(v1 + EPSf), r2 = rsqrtf(v2 + EPSf), r3 = rsqrtf(v3 + EPSf);
    float Kc = m1*r1 + m2*r2 + m3*r3;

    float cw0[9], cwA[9], cwB[9];
    #pragma unroll
    for (int ij = 0; ij < 9; ++ij) {
        cw0[ij] = r1*swk[ij]      + r2*swk[27+ij] + r3*swk[54+ij];
        cwA[ij] = r1*swk[9+ij]    + r2*swk[45+ij];
        cwB[ij] = r1*swk[18+ij]   + r2*swk[36+ij];
    }

    const float* ch = in + ((size_t)(b*Cn + rep_idx[r]))*HWn;
    float* dst = out + ((size_t)(b*Cn + c))*HWn;
    conv_walk1(ch, cw0, cwA, cwB, Kc, tid, dst);
}

extern "C" void kernel_launch(void* const* d_in, const int* in_sizes, int n_in,
                              void* d_out, int out_size, void* d_ws, size_t ws_size,
                              hipStream_t stream) {
    const float* in   = (const float*)d_in[0];
    const float* w0   = (const float*)d_in[1];
    const float* w1   = (const float*)d_in[2];
    const int*   Mh   = (const int*)d_in[3];
    const int*   Mv   = (const int*)d_in[4];
    const int*   Mid  = (const int*)d_in[5];
    const int*   ghost= (const int*)d_in[6];
    const int*   rep  = (const int*)d_in[7];
    float* out  = (float*)d_out;
    float* ws   = (float*)d_ws;

    // Plain 2-kernel chain: graph-capturable, no gates, no cross-block sync.
    k_pass1<<<REPN*Bn, 128, 0, stream>>>(in, w0, w1, Mh, Mv, Mid, rep, ws);
    k_pass2<<<Bn*Cn,   128, 0, stream>>>(in, w0, w1, Mh, Mv, Mid, rep, ghost, ws, out);
}

// Round 7
// 117.946 us; speedup vs baseline: 1.1426x; 1.0147x over previous
//
#include <hip/hip_runtime.h>

#define Bn 32
#define Cn 64
#define Hn 56
#define Wn 56
#define REPN 50
#define NKn 17
#define HWn (Hn*Wn)           // 3136
#define NSTATf 100352.0f      // B*H*W
#define EPSf 1e-5f

// ---- fused-kernel ws layout (zeroed by hipMemsetAsync each iteration) ----
#define GCNT_OFF 0            // unsigned [r(50)][32] (128B stride) = 1600 ints
#define GSUM_OFF 1600         // float [r(50)][8] = 400 floats (6 used)
#define INIT_BYTES 8000       // bytes 0..8000 zeroed
// ---- fallback-chain scratch (disjoint) ----
#define PART_OFF 4096         // [stat(6)][r(50)][b(32)] = 9600

#define SEGH 7
#define NTASK 112             // 8 row-segments * 14 quad-cols
#define GRID_FUSED 1024       // 4 blocks/CU -> co-resident at any VGPR<=256

// ---------------------------------------------------------------- weff in LDS
// swk layout t-major: swk[t*9+ij]; t: 0..2 Mh shifts, 3..5 Mv shifts, 6 Mid.
__device__ __forceinline__ void block_weff(int r, int tid,
        const float* __restrict__ w0, const float* __restrict__ w1,
        const int* __restrict__ Mh, const int* __restrict__ Mv,
        const int* __restrict__ Mid, float* __restrict__ swk)
{
    if (tid >= 0 && tid < 63) {
        int t = tid / 9, ij = tid - t*9;
        const int* M = (t < 3) ? (Mh + (t*REPN + r)*NKn)
                     : (t < 6) ? (Mv + ((t-3)*REPN + r)*NKn)
                               : (Mid + r*NKn);
        float acc = 0.f;
        #pragma unroll
        for (int k = 0; k < NKn; ++k)
            acc += (float)M[k] * (w0[(r*NKn + k)*9 + ij] + w1[(r*NKn + k)*9 + ij]);
        swk[t*9 + ij] = acc;
    }
}

// Load input row `row` of channel ch as window X[0..7] = cols 4q-3..4q+4
// (zeros outside [0,56)). Also c55 = input[row][55] for q==0 lanes.
__device__ __forceinline__ void load_row8c(const float* __restrict__ ch, int row, int q,
                                           float* __restrict__ X, float& c55)
{
    bool rv = (row >= 0) && (row < Hn);
    int rc = rv ? row : 0;
    const float* rp = ch + rc*Wn;
    float4 c0 = *(const float4*)(rp + (q ? 4*q - 4 : 0));   // cols 4q-4..4q-1
    float4 c1 = *(const float4*)(rp + 4*q);                 // cols 4q..4q+3
    int ox = (4*q + 4 <= 55) ? 4*q + 4 : 55;                // clamp in-row
    float cx = rp[ox];
    float mr = rv ? 1.f : 0.f;
    float m0 = (rv && q > 0)  ? 1.f : 0.f;
    float mx = (rv && q < 13) ? 1.f : 0.f;
    X[0]=c0.y*m0; X[1]=c0.z*m0; X[2]=c0.w*m0;
    X[3]=c1.x*mr; X[4]=c1.y*mr; X[5]=c1.z*mr; X[6]=c1.w*mr;
    X[7]=cx*mx;
    c55 = (q == 0) ? rp[55]*mr : 0.f;
}

// -------------------------------------------- 3-accumulator walk (stats pass)
// 6-row rolling window, 2-row prefetch lookahead (R6-proven).
template <typename F>
__device__ __forceinline__ void conv_walk3(const float* __restrict__ ch,
        const float (&wk)[63], int tid, F emit)
{
    if (tid >= NTASK) return;
    int seg = tid / 14;
    int q   = tid - seg*14;
    int h0  = seg * SEGH;
    bool top = (seg == 0);

    float W[6][8], C[6], T[8];
    {
        float dummy;
        if (top) load_row8c(ch, 55, q, T, dummy);
    }
    #pragma unroll
    for (int k = 0; k < 6; ++k)
        load_row8c(ch, h0 - 3 + k, q, W[k], C[k]);

    #pragma unroll
    for (int s = 0; s < SEGH; ++s) {
        int h = h0 + s;
        float Wn8[8], Cn1;
        load_row8c(ch, h + 3, q, Wn8, Cn1);   // prefetch 2 rows ahead

        float l1[4], l2[4], sm[4];
        #pragma unroll
        for (int p = 0; p < 4; ++p) { l1[p]=0.f; l2[p]=0.f; sm[p]=0.f; }
        #pragma unroll
        for (int i = 0; i < 3; ++i)
            #pragma unroll
            for (int j = 0; j < 3; ++j) {
                int ij = i*3 + j;
                float wh0 = wk[ij],    wh1 = wk[9+ij],  wh2 = wk[18+ij];
                float wv0 = wk[27+ij], wv1 = wk[36+ij], wv2 = wk[45+ij];
                float wid = wk[54+ij];
                #pragma unroll
                for (int p = 0; p < 4; ++p) {
                    float a  = W[2+i][p+2+j];     // pos0
                    l1[p] = fmaf(a, wh0, l1[p]);
                    l2[p] = fmaf(a, wv0, l2[p]);
                    sm[p] = fmaf(a, wid, sm[p]);
                    float bA = W[1+i][p+j];       // posA
                    l1[p] = fmaf(bA, wh1, l1[p]);
                    l2[p] = fmaf(bA, wv2, l2[p]);
                    float bB = W[i][p+1+j];       // posB
                    l1[p] = fmaf(bB, wh2, l1[p]);
                    l2[p] = fmaf(bB, wv1, l2[p]);
                }
            }
        if (q == 0) {   // col wrap, pixel 0: posA j=0 -> t1 (l1), t5 (l2)
            #pragma unroll
            for (int i = 0; i < 3; ++i) {
                l1[0] = fmaf(C[1+i], wk[9+3*i],  l1[0]);
                l2[0] = fmaf(C[1+i], wk[45+3*i], l2[0]);
            }
        }
        if (s == 0 && top) {   // row wrap, h==0: posB i=0 -> t2 (l1), t4 (l2)
            #pragma unroll
            for (int j = 0; j < 3; ++j)
                #pragma unroll
                for (int p = 0; p < 4; ++p) {
                    l1[p] = fmaf(T[p+1+j], wk[18+j], l1[p]);
                    l2[p] = fmaf(T[p+1+j], wk[36+j], l2[p]);
                }
        }
        float res[4] = {W[3][3], W[3][4], W[3][5], W[3][6]};
        emit(h, q, l1, l2, sm, res);

        #pragma unroll
        for (int k = 0; k < 5; ++k) {
            #pragma unroll
            for (int x = 0; x < 8; ++x) W[k][x] = W[k+1][x];
            C[k] = C[k+1];
        }
        #pragma unroll
        for (int x = 0; x < 8; ++x) W[5][x] = Wn8[x];
        C[5] = Cn1;
    }
}

// ------------------------------- single-accumulator walk (BN-folded output)
__device__ __forceinline__ void conv_walk1(const float* __restrict__ ch,
        const float (&cw0)[9], const float (&cwA)[9], const float (&cwB)[9],
        float Kc, int tid, float* __restrict__ dst)
{
    if (tid >= NTASK) return;
    int seg = tid / 14;
    int q   = tid - seg*14;
    int h0  = seg * SEGH;
    bool top = (seg == 0);

    float W[6][8], C[6], T[8];
    {
        float dummy;
        if (top) load_row8c(ch, 55, q, T, dummy);
    }
    #pragma unroll
    for (int k = 0; k < 6; ++k)
        load_row8c(ch, h0 - 3 + k, q, W[k], C[k]);

    #pragma unroll
    for (int s = 0; s < SEGH; ++s) {
        int h = h0 + s;
        float Wn8[8], Cn1;
        load_row8c(ch, h + 3, q, Wn8, Cn1);   // prefetch 2 rows ahead

        float acc[4];
        #pragma unroll
        for (int p = 0; p < 4; ++p) acc[p] = 0.f;
        #pragma unroll
        for (int i = 0; i < 3; ++i)
            #pragma unroll
            for (int j = 0; j < 3; ++j) {
                int ij = i*3 + j;
                float w0c = cw0[ij], wAc = cwA[ij], wBc = cwB[ij];
                #pragma unroll
                for (int p = 0; p < 4; ++p) {
                    acc[p] = fmaf(W[2+i][p+2+j], w0c, acc[p]);   // pos0
                    acc[p] = fmaf(W[1+i][p+j],   wAc, acc[p]);   // posA
                    acc[p] = fmaf(W[i][p+1+j],   wBc, acc[p]);   // posB
                }
            }
        if (q == 0) {   // col wrap, pixel 0: posA j=0
            #pragma unroll
            for (int i = 0; i < 3; ++i)
                acc[0] = fmaf(C[1+i], cwA[3*i], acc[0]);
        }
        if (s == 0 && top) {   // row wrap, h==0: posB i=0
            #pragma unroll
            for (int j = 0; j < 3; ++j)
                #pragma unroll
                for (int p = 0; p < 4; ++p)
                    acc[p] = fmaf(T[p+1+j], cwB[j], acc[p]);
        }
        float4 o;
        o.x = acc[0] - Kc + W[3][3];
        o.y = acc[1] - Kc + W[3][4];
        o.z = acc[2] - Kc + W[3][5];
        o.w = acc[3] - Kc + W[3][6];
        *(float4*)(dst + h*Wn + 4*q) = o;

        #pragma unroll
        for (int k = 0; k < 5; ++k) {
            #pragma unroll
            for (int x = 0; x < 8; ++x) W[k][x] = W[k+1][x];
            C[k] = C[k+1];
        }
        #pragma unroll
        for (int x = 0; x < 8; ++x) W[5][x] = Wn8[x];
        C[5] = Cn1;
    }
}

// ------------------------------------------------ helpers for fused kernel
__device__ __forceinline__ void stats_and_arrive(const float* __restrict__ ch,
        const float* __restrict__ swk, int r, int tid,
        float* __restrict__ ws, float (*red)[6])
{
    float wk[63];
    #pragma unroll
    for (int i = 0; i < 63; ++i) wk[i] = swk[i];

    float s1=0.f,q1=0.f,s2=0.f,q2=0.f,s3=0.f,q3=0.f;
    conv_walk3(ch, wk, tid,
        [&](int h, int q, float* l1, float* l2, float* sm, float* res) {
            (void)h; (void)q; (void)res;
            #pragma unroll
            for (int p = 0; p < 4; ++p) {
                s1 += l1[p]; q1 += l1[p]*l1[p];
                s2 += l2[p]; q2 += l2[p]*l2[p];
                s3 += sm[p]; q3 += sm[p]*sm[p];
            }
        });
    {
        float vals[6] = {s1,q1,s2,q2,s3,q3};
        int lane = tid & 63, wave = tid >> 6;
        #pragma unroll
        for (int x = 0; x < 6; ++x) {
            float y = vals[x];
            for (int o = 32; o; o >>= 1) y += __shfl_down(y, o, 64);
            if (lane == 0) red[wave][x] = y;
        }
    }
    __syncthreads();
    if (tid < 6) {
        atomicAdd(ws + GSUM_OFF + r*8 + tid, red[0][tid] + red[1][tid]);
        __threadfence();                       // release: sums visible first
    }
    __syncthreads();
    if (tid == 0)
        atomicAdd(((unsigned*)ws) + GCNT_OFF + r*32, 1u);
    // no barrier needed here; next phase has its own syncs before red reuse
    __syncthreads();
}

__device__ __forceinline__ void wait_and_finalize(const float* __restrict__ ch,
        const float* __restrict__ swk, int r, int tid,
        float* __restrict__ ws, float* __restrict__ sred,
        float* __restrict__ dst)
{
    if (tid == 0) {
        unsigned* gc = ((unsigned*)ws) + GCNT_OFF + r*32;
        while (atomicAdd(gc, 0u) < (unsigned)Bn)
            __builtin_amdgcn_s_sleep(8);
    }
    __syncthreads();                           // acquire for whole block
    if (tid < 6) sred[tid] = atomicAdd(ws + GSUM_OFF + r*8 + tid, 0.f);
    __syncthreads();

    const float inv = 1.0f / NSTATf;
    float m1 = sred[0]*inv, v1 = sred[1]*inv - m1*m1;
    float m2 = sred[2]*inv, v2 = sred[3]*inv - m2*m2;
    float m3 = sred[4]*inv, v3 = sred[5]*inv - m3*m3;
    float r1 = rsqrtf(v1 + EPSf), r2 = rsqrtf(v2 + EPSf), r3 = rsqrtf(v3 + EPSf);
    float Kc = m1*r1 + m2*r2 + m3*r3;

    float cw0[9], cwA[9], cwB[9];
    #pragma unroll
    for (int ij = 0; ij < 9; ++ij) {
        cw0[ij] = r1*swk[ij]    + r2*swk[27+ij] + r3*swk[54+ij];
        cwA[ij] = r1*swk[9+ij]  + r2*swk[45+ij];
        cwB[ij] = r1*swk[18+ij] + r2*swk[36+ij];
    }
    conv_walk1(ch, cw0, cwA, cwB, Kc, tid, dst);
}

// --------------------------------------------- fused single kernel (plain)
// 1024 blocks x 128. Block bid = b*32 + pr owns tasks (b, 2pr) and (b, 2pr+1).
// REPN=50 even -> pairs homogeneous: pr<25 rep, pr>=25 ghost.
// Rep: weff(A)||weff(B) -> stats+arrive(A) -> stats+arrive(B) ->
//      wait+finalize(A) -> wait+finalize(B). All arrivals precede all waits;
// 4 blocks/CU co-resident at any VGPR<=256 -> spin is deadlock-free.
// Cross-block protocol: gsum atomicAdd + threadfence + gcnt atomicAdd
// (release); spin on atomic read + atomic gsum reads (acquire).
__global__ void __launch_bounds__(128) k_fused(const float* __restrict__ in,
        const float* __restrict__ w0, const float* __restrict__ w1,
        const int* __restrict__ Mh, const int* __restrict__ Mv,
        const int* __restrict__ Mid,
        const int* __restrict__ rep_idx, const int* __restrict__ ghost_idx,
        float* __restrict__ ws, float* __restrict__ out)
{
    int tid = threadIdx.x;
    int bid = blockIdx.x;         // 0..1023
    int b   = bid >> 5;           // 0..31
    int pr  = bid & 31;           // pair index 0..31
    int cA  = 2*pr, cB = 2*pr + 1;

    if (pr >= REPN/2) {           // ghost pair: two copies, retire
        #pragma unroll
        for (int it = 0; it < 2; ++it) {
            int c = cA + it;
            int cin = ghost_idx[c - REPN];
            const float4* s4 = (const float4*)(in + ((size_t)(b*Cn + cin))*HWn);
            float4* d4 = (float4*)(out + ((size_t)(b*Cn + c))*HWn);
            for (int i = tid; i < HWn/4; i += 128) d4[i] = s4[i];
        }
        return;
    }

    __shared__ float swkA[63], swkB[63];
    __shared__ float red[2][6];
    __shared__ float sredA[6], sredB[6];

    // weff for both tasks, one wave each
    block_weff(cA, tid,      w0, w1, Mh, Mv, Mid, swkA);
    block_weff(cB, tid - 64, w0, w1, Mh, Mv, Mid, swkB);
    __syncthreads();

    const float* chA = in + ((size_t)(b*Cn + rep_idx[cA]))*HWn;
    const float* chB = in + ((size_t)(b*Cn + rep_idx[cB]))*HWn;

    stats_and_arrive(chA, swkA, cA, tid, ws, red);
    stats_and_arrive(chB, swkB, cB, tid, ws, red);

    float* dstA = out + ((size_t)(b*Cn + cA))*HWn;
    float* dstB = out + ((size_t)(b*Cn + cB))*HWn;
    wait_and_finalize(chA, swkA, cA, tid, ws, sredA, dstA);
    wait_and_finalize(chB, swkB, cB, tid, ws, sredB, dstB);
}

// ------------------------------------- fallback: proven R6 2-kernel chain
__global__ void __launch_bounds__(128) k_pass1(const float* __restrict__ in,
        const float* __restrict__ w0, const float* __restrict__ w1,
        const int* __restrict__ Mh, const int* __restrict__ Mv,
        const int* __restrict__ Mid,
        const int* __restrict__ rep_idx, float* __restrict__ ws)
{
    int bid = blockIdx.x;
    int r = bid % REPN;
    int b = bid / REPN;
    int tid = threadIdx.x;

    __shared__ float swk[63];
    __shared__ float red[2][6];

    block_weff(r, tid, w0, w1, Mh, Mv, Mid, swk);
    __syncthreads();
    float wk[63];
    #pragma unroll
    for (int i = 0; i < 63; ++i) wk[i] = swk[i];

    const float* ch = in + ((size_t)(b*Cn + rep_idx[r]))*HWn;

    float s1=0.f,q1=0.f,s2=0.f,q2=0.f,s3=0.f,q3=0.f;
    conv_walk3(ch, wk, tid,
        [&](int h, int q, float* l1, float* l2, float* sm, float* res) {
            (void)h; (void)q; (void)res;
            #pragma unroll
            for (int p = 0; p < 4; ++p) {
                s1 += l1[p]; q1 += l1[p]*l1[p];
                s2 += l2[p]; q2 += l2[p]*l2[p];
                s3 += sm[p]; q3 += sm[p]*sm[p];
            }
        });

    float vals[6] = {s1,q1,s2,q2,s3,q3};
    int lane = tid & 63, wave = tid >> 6;
    #pragma unroll
    for (int x = 0; x < 6; ++x) {
        float y = vals[x];
        for (int o = 32; o; o >>= 1) y += __shfl_down(y, o, 64);
        if (lane == 0) red[wave][x] = y;
    }
    __syncthreads();
    if (tid < 6)
        ws[PART_OFF + (tid*REPN + r)*Bn + b] = red[0][tid] + red[1][tid];
}

__global__ void __launch_bounds__(128) k_pass2(const float* __restrict__ in,
        const float* __restrict__ w0, const float* __restrict__ w1,
        const int* __restrict__ Mh, const int* __restrict__ Mv,
        const int* __restrict__ Mid,
        const int* __restrict__ rep_idx, const int* __restrict__ ghost_idx,
        const float* __restrict__ ws, float* __restrict__ out)
{
    int bid = blockIdx.x;
    int c = bid & 63;
    int b = bid >> 6;
    int tid = threadIdx.x;

    if (c >= REPN) {
        int cin = ghost_idx[c - REPN];
        const float4* s4 = (const float4*)(in + ((size_t)(b*Cn + cin))*HWn);
        float4* d4 = (float4*)(out + ((size_t)(b*Cn + c))*HWn);
        for (int i = tid; i < HWn/4; i += 128) d4[i] = s4[i];
        return;
    }
    int r = c;

    __shared__ float swk[63];
    __shared__ float sred[6];

    block_weff(r, tid, w0, w1, Mh, Mv, Mid, swk);
    if (tid >= 64 && tid < 70) {
        int x = tid - 64;
        const float* pp = ws + PART_OFF + (x*REPN + r)*Bn;
        float s = 0.f;
        #pragma unroll
        for (int i = 0; i < Bn; ++i) s += pp[i];
        sred[x] = s;
    }
    __syncthreads();

    const float inv = 1.0f / NSTATf;
    float m1 = sred[0]*inv, v1 = sred[1]*inv - m1*m1;
    float m2 = sred[2]*inv, v2 = sred[3]*inv - m2*m2;
    float m3 = sred[4]*inv, v3 = sred[5]*inv - m3*m3;
    float r1 = rsqrtf(v1 + EPSf), r2 = rsqrtf(v2 + EPSf), r3 = rsqrtf(v3 + EPSf);
    float Kc = m1*r1 + m2*r2 + m3*r3;

    float cw0[9], cwA[9], cwB[9];
    #pragma unroll
    for (int ij = 0; ij < 9; ++ij) {
        cw0[ij] = r1*swk[ij]    + r2*swk[27+ij] + r3*swk[54+ij];
        cwA[ij] = r1*swk[9+ij]  + r2*swk[45+ij];
        cwB[ij] = r1*swk[18+ij] + r2*swk[36+ij];
    }

    const float* ch = in + ((size_t)(b*Cn + rep_idx[r]))*HWn;
    float* dst = out + ((size_t)(b*Cn + c))*HWn;
    conv_walk1(ch, cw0, cwA, cwB, Kc, tid, dst);
}

extern "C" void kernel_launch(void* const* d_in, const int* in_sizes, int n_in,
                              void* d_out, int out_size, void* d_ws, size_t ws_size,
                              hipStream_t stream) {
    const float* in   = (const float*)d_in[0];
    const float* w0   = (const float*)d_in[1];
    const float* w1   = (const float*)d_in[2];
    const int*   Mh   = (const int*)d_in[3];
    const int*   Mv   = (const int*)d_in[4];
    const int*   Mid  = (const int*)d_in[5];
    const int*   ghost= (const int*)d_in[6];
    const int*   rep  = (const int*)d_in[7];
    float* out  = (float*)d_out;
    float* ws   = (float*)d_ws;

    // Spin-safety gate: need 4 blocks/CU co-resident (structurally true at
    // any VGPR<=256; queried anyway). Capture-safe host-side query.
    int maxBlk = 0;
    hipError_t qerr = hipOccupancyMaxActiveBlocksPerMultiprocessor(
        &maxBlk, (const void*)k_fused, 128, 0);
    bool fused_ok = (qerr == hipSuccess) && (maxBlk >= 4);

    if (fused_ok) {
        hipError_t merr = hipMemsetAsync(ws, 0, INIT_BYTES, stream);
        if (merr == hipSuccess) {
            k_fused<<<GRID_FUSED, 128, 0, stream>>>(in, w0, w1, Mh, Mv, Mid,
                                                    rep, ghost, ws, out);
            return;
        }
    }
    // Fallback: proven R6 2-kernel chain
    k_pass1<<<REPN*Bn, 128, 0, stream>>>(in, w0, w1, Mh, Mv, Mid, rep, ws);
    k_pass2<<<Bn*Cn,   128, 0, stream>>>(in, w0, w1, Mh, Mv, Mid, rep, ghost, ws, out);
}